// Round 5
// baseline (749.357 us; speedup 1.0000x reference)
//
#include <hip/hip_runtime.h>
#include <math.h>

#define TPB 256
#define GRP 16                        // lanes per voxel group in reduce
#define VPB 32                        // voxels per bucket
#define CAP 2048                      // max rows per bucket (fast path); mean=1024, sigma=32
#define EPSF 1e-6f
#define LOG_G1 -2.3025850929940457f   /* log(0.1) */
#define LOGEPS -13.815510557964274f   /* log(1e-6) */

// ---- 16-lane-group butterfly reductions (4 voxels per wave64) ----
__device__ __forceinline__ float gsum16(float x){
  #pragma unroll
  for (int k = 8; k >= 1; k >>= 1) x += __shfl_xor(x, k, 64);
  return x;
}
__device__ __forceinline__ float gmax16(float x){
  #pragma unroll
  for (int k = 8; k >= 1; k >>= 1) x = fmaxf(x, __shfl_xor(x, k, 64));
  return x;
}
__device__ __forceinline__ float score_from(float gt, float c, float t0){
  float g0 = fmaxf(c, EPSF);
  float dt = t0 - gt;
  // log(max(exp(sigma*dt^2),EPS))/T == max(sigma*dt^2, logEPS)/T exactly
  return fmaxf(LOG_G1 / (g0 * g0 + EPSF) * dt * dt, LOGEPS) / 0.07f;
}

// ---------------- zero bucket counters ----------------
__global__ void k_zero(unsigned* __restrict__ p, int n){
  int i = blockIdx.x * TPB + threadIdx.x;
  if (i < n) p[i] = 0u;
}

// ---------------- bucket histogram ----------------
__global__ void k_bcount(const int* __restrict__ vox, unsigned* __restrict__ bcnt, int N){
  int i = blockIdx.x * TPB + threadIdx.x;
  if (i >= N) return;
  atomicAdd(&bcnt[vox[i] >> 5], 1u);
}

// ---------------- exclusive scan of NB bucket counts (single block) ----------------
__global__ void k_bscan(const unsigned* __restrict__ bcnt, unsigned* __restrict__ bofs,
                        unsigned* __restrict__ bcur, int NB){
  __shared__ unsigned sm[TPB];
  unsigned carry = 0;
  for (int base = 0; base < NB; base += TPB){
    int i = base + threadIdx.x;
    unsigned v = (i < NB) ? bcnt[i] : 0u;
    sm[threadIdx.x] = v;
    __syncthreads();
    for (int off = 1; off < TPB; off <<= 1){
      unsigned t = (threadIdx.x >= off) ? sm[threadIdx.x - off] : 0u;
      __syncthreads();
      sm[threadIdx.x] += t;
      __syncthreads();
    }
    if (i < NB){
      unsigned e = carry + sm[threadIdx.x] - v;
      bofs[i] = e; bcur[i] = e;
    }
    carry += sm[TPB - 1];
    __syncthreads();
  }
}

// ---------------- build: transform + full-line bucketed append ----------------
// row (16 floats = one 64B line): [f0..f6, log(f7..f9), f10..f13, score, vlow]
__global__ __launch_bounds__(TPB)
void k_build(const float* __restrict__ feat, const float* __restrict__ conf,
             const int* __restrict__ vox, const float* __restrict__ tt,
             unsigned* __restrict__ bcur, float* __restrict__ rows,
             float* __restrict__ S, int N){
  __shared__ float sf[TPB * 15];
  int base = blockIdx.x * TPB;
  int nrow = N - base; if (nrow > TPB) nrow = TPB;
  int nflt = nrow * 15;
  if (nflt == TPB * 15){
    const float4* g4 = (const float4*)(feat + (size_t)base * 15);
    float4* s4 = (float4*)sf;
    #pragma unroll
    for (int k = 0; k < 4; ++k){
      int j = threadIdx.x + k * TPB;
      if (j < TPB * 15 / 4) s4[j] = g4[j];
    }
  } else {
    for (int j = threadIdx.x; j < nflt; j += TPB)
      sf[j] = feat[(size_t)base * 15 + j];
  }
  __syncthreads();
  int t = threadIdx.x;
  if (t >= nrow) return;
  int i = base + t;
  float r[15];
  #pragma unroll
  for (int c = 0; c < 15; ++c) r[c] = sf[t * 15 + c];      // stride 15: conflict-free
  float score = score_from(r[14], conf[i], tt[0]);
  r[7] = logf(fmaxf(r[7], 1e-6f));
  r[8] = logf(fmaxf(r[8], 1e-6f));
  r[9] = logf(fmaxf(r[9], 1e-6f));
  S[i] = score;                                            // linear score write (in W buffer)
  int v = vox[i];
  unsigned rk = atomicAdd(&bcur[v >> 5], 1u);
  float4* p4 = (float4*)(rows + (size_t)rk * 16);          // one FULL 64B line per row
  p4[0] = make_float4(r[0],  r[1],  r[2],  r[3]);
  p4[1] = make_float4(r[4],  r[5],  r[6],  r[7]);
  p4[2] = make_float4(r[8],  r[9],  r[10], r[11]);
  p4[3] = make_float4(r[12], r[13], score, __uint_as_float((unsigned)(v & (VPB - 1))));
}

// ---------------- per-bucket reduce: LDS sort + L2-hot gathers ----------------
__global__ __launch_bounds__(TPB)
void k_breduce(const float* __restrict__ rows, const unsigned* __restrict__ bofs,
               const unsigned* __restrict__ bcnt, float* __restrict__ F,
               float* __restrict__ mArr, float* __restrict__ invArr, int M){
  __shared__ float          ssc[CAP];          // scores
  __shared__ unsigned char  svl[CAP];          // local voxel ids
  __shared__ unsigned short ssx[CAP];          // sorted row indices
  __shared__ unsigned lcnt[VPB + 1], lofs[VPB + 1];
  __shared__ float Fst[VPB * 15];              // coalesced F staging
  __shared__ float mSt[VPB], iSt[VPB];

  int b = blockIdx.x;
  unsigned base = bofs[b], L = bcnt[b];
  int v0 = b * VPB;
  int g  = threadIdx.x / GRP;                  // 0..15
  int sl = threadIdx.x & (GRP - 1);

  if (L <= CAP){
    // stream (score, vlow): contiguous lines -> warms L2 with the whole bucket
    for (unsigned j = threadIdx.x; j < L; j += TPB){
      float2 q = *(const float2*)(rows + (size_t)(base + j) * 16 + 14);
      ssc[j] = q.x;
      svl[j] = (unsigned char)__float_as_uint(q.y);
    }
    if (threadIdx.x <= VPB) lcnt[threadIdx.x] = 0u;
    __syncthreads();
    for (unsigned j = threadIdx.x; j < L; j += TPB) atomicAdd(&lcnt[svl[j]], 1u);
    __syncthreads();
    if (threadIdx.x == 0){
      unsigned s = 0;
      for (int k = 0; k < VPB; ++k){ lofs[k] = s; s += lcnt[k]; }
      lofs[VPB] = s;
    }
    __syncthreads();
    if (threadIdx.x < VPB) lcnt[threadIdx.x] = lofs[threadIdx.x];   // reuse as cursor
    __syncthreads();
    for (unsigned j = threadIdx.x; j < L; j += TPB){
      unsigned rk = atomicAdd(&lcnt[svl[j]], 1u);
      ssx[rk] = (unsigned short)j;
    }
    __syncthreads();

    for (int vv = g; vv < VPB; vv += TPB / GRP){
      unsigned s0 = lofs[vv], Lv = lofs[vv + 1] - s0;
      float m = -INFINITY;
      for (unsigned j = sl; j < Lv; j += GRP) m = fmaxf(m, ssc[ssx[s0 + j]]);
      m = gmax16(m);
      float se = 0.f, mop = -INFINITY;
      float a0=0,a1=0,a2=0,a3=0,a4=0,a5=0,a6=0,a7=0,a8=0,a9=0,a10=0,a11=0,a12=0,a13=0;
      for (unsigned j = sl; j < Lv; j += GRP){
        unsigned rj = ssx[s0 + j];
        const float* rp = rows + (size_t)(base + rj) * 16;   // L2-hot
        float4 q0 = *(const float4*)(rp);
        float4 q1 = *(const float4*)(rp + 4);
        float4 q2 = *(const float4*)(rp + 8);
        float2 q3 = *(const float2*)(rp + 12);
        float e = expf(ssc[rj] - m);
        se += e;
        mop = fmaxf(mop, q1.z);
        a0 += q0.x*e; a1 += q0.y*e; a2  += q0.z*e; a3  += q0.w*e;
        a4 += q1.x*e; a5 += q1.y*e; a6  += q1.z*e; a7  += q1.w*e;
        a8 += q2.x*e; a9 += q2.y*e; a10 += q2.z*e; a11 += q2.w*e;
        a12 += q3.x*e; a13 += q3.y*e;
      }
      se  = gsum16(se);
      a0  = gsum16(a0);  a1  = gsum16(a1);  a2  = gsum16(a2);  a3  = gsum16(a3);
      a4  = gsum16(a4);  a5  = gsum16(a5);  a6  = gsum16(a6);  a7  = gsum16(a7);
      a8  = gsum16(a8);  a9  = gsum16(a9);  a10 = gsum16(a10); a11 = gsum16(a11);
      a12 = gsum16(a12); a13 = gsum16(a13);
      mop = gmax16(mop);
      if (sl == 0){
        float inv = (Lv > 0u) ? 1.0f / se : 0.0f;
        mSt[vv] = (Lv > 0u) ? m : 0.0f;
        iSt[vv] = inv;
        float* f = &Fst[vv * 15];
        float b6 = a6 * inv;
        float maxop = (Lv > 0u) ? mop : 0.0f;
        f[0] = a0*inv; f[1] = a1*inv; f[2] = a2*inv;
        f[3] = a3*inv; f[4] = a4*inv; f[5] = a5*inv;
        f[6] = 0.7f * maxop + 0.3f * b6;
        f[7] = expf(a7*inv); f[8] = expf(a8*inv); f[9] = expf(a9*inv);
        float r0 = a10*inv, r1 = a11*inv, r2 = a12*inv, r3 = a13*inv;
        float nrm  = sqrtf(r0*r0 + r1*r1 + r2*r2 + r3*r3);
        float rinv = 1.0f / fmaxf(nrm, 1e-6f);
        f[10] = r0*rinv; f[11] = r1*rinv; f[12] = r2*rinv; f[13] = r3*rinv;
        f[14] = 0.0f;
      }
    }
    __syncthreads();
    // coalesced output writes
    int lim = M - v0; if (lim > VPB) lim = VPB;
    for (int j = threadIdx.x; j < lim * 15; j += TPB)
      F[(size_t)v0 * 15 + j] = Fst[j];
    if (threadIdx.x < lim){
      mArr[v0 + threadIdx.x]   = mSt[threadIdx.x];
      invArr[v0 + threadIdx.x] = iSt[threadIdx.x];
    }
  } else {
    // ---- fallback (bucket overflow; statistically never at this distribution) ----
    for (int vv = g; vv < VPB; vv += TPB / GRP){
      float m = -INFINITY;
      for (unsigned j = sl; j < L; j += GRP){
        float2 q = *(const float2*)(rows + (size_t)(base + j) * 16 + 14);
        if (__float_as_uint(q.y) == (unsigned)vv) m = fmaxf(m, q.x);
      }
      m = gmax16(m);
      float se = 0.f, mop = -INFINITY;
      float a0=0,a1=0,a2=0,a3=0,a4=0,a5=0,a6=0,a7=0,a8=0,a9=0,a10=0,a11=0,a12=0,a13=0;
      unsigned nv = 0;
      for (unsigned j = sl; j < L; j += GRP){
        const float* rp = rows + (size_t)(base + j) * 16;
        float2 q3h = *(const float2*)(rp + 14);
        if (__float_as_uint(q3h.y) != (unsigned)vv) continue;
        ++nv;
        float4 q0 = *(const float4*)(rp);
        float4 q1 = *(const float4*)(rp + 4);
        float4 q2 = *(const float4*)(rp + 8);
        float2 q3 = *(const float2*)(rp + 12);
        float e = expf(q3h.x - m);
        se += e;
        mop = fmaxf(mop, q1.z);
        a0 += q0.x*e; a1 += q0.y*e; a2  += q0.z*e; a3  += q0.w*e;
        a4 += q1.x*e; a5 += q1.y*e; a6  += q1.z*e; a7  += q1.w*e;
        a8 += q2.x*e; a9 += q2.y*e; a10 += q2.z*e; a11 += q2.w*e;
        a12 += q3.x*e; a13 += q3.y*e;
      }
      se  = gsum16(se);
      a0  = gsum16(a0);  a1  = gsum16(a1);  a2  = gsum16(a2);  a3  = gsum16(a3);
      a4  = gsum16(a4);  a5  = gsum16(a5);  a6  = gsum16(a6);  a7  = gsum16(a7);
      a8  = gsum16(a8);  a9  = gsum16(a9);  a10 = gsum16(a10); a11 = gsum16(a11);
      a12 = gsum16(a12); a13 = gsum16(a13);
      mop = gmax16(mop);
      nv  = (unsigned)gsum16((float)nv);
      if (sl == 0 && v0 + vv < M){
        bool has = nv > 0u;
        float inv = has ? 1.0f / se : 0.0f;
        mArr[v0 + vv]   = has ? m : 0.0f;
        invArr[v0 + vv] = inv;
        float* f = F + (size_t)(v0 + vv) * 15;
        float maxop = has ? mop : 0.0f;
        f[0] = a0*inv; f[1] = a1*inv; f[2] = a2*inv;
        f[3] = a3*inv; f[4] = a4*inv; f[5] = a5*inv;
        f[6] = 0.7f * maxop + 0.3f * (a6*inv);
        f[7] = expf(a7*inv); f[8] = expf(a8*inv); f[9] = expf(a9*inv);
        float r0 = a10*inv, r1 = a11*inv, r2 = a12*inv, r3 = a13*inv;
        float nrm  = sqrtf(r0*r0 + r1*r1 + r2*r2 + r3*r3);
        float rinv = 1.0f / fmaxf(nrm, 1e-6f);
        f[10] = r0*rinv; f[11] = r1*rinv; f[12] = r2*rinv; f[13] = r3*rinv;
        f[14] = 0.0f;
      }
    }
  }
}

// ---------------- final: linear weight normalization ----------------
__global__ void k_wfinal(const int* __restrict__ vox, const float* __restrict__ mArr,
                         const float* __restrict__ invArr, float* __restrict__ W, int N){
  int i = blockIdx.x * TPB + threadIdx.x;
  if (i >= N) return;
  int v = vox[i];
  W[i] = expf(W[i] - mArr[v]) * invArr[v];   // W held raw score
}

extern "C" void kernel_launch(void* const* d_in, const int* in_sizes, int n_in,
                              void* d_out, int out_size, void* d_ws, size_t ws_size,
                              hipStream_t stream) {
  const float* feat = (const float*)d_in[0];
  const int*   vox  = (const int*)  d_in[1];
  const float* tt   = (const float*)d_in[3];
  const float* conf = (const float*)d_in[4];

  int N  = in_sizes[0] / 15;
  int M  = (out_size - N) / 15;
  int NB = (M + VPB - 1) / VPB;

  float* F = (float*)d_out;                      // fused gaussians: M*15
  float* W = (float*)d_out + (size_t)M * 15;     // weights: N (holds score, then w)

  unsigned* bcnt = (unsigned*)d_ws;              // NB
  unsigned* bofs = bcnt + NB;                    // NB
  unsigned* bcur = bofs + NB;                    // NB
  float*    mArr = (float*)(bcur + NB);          // M
  float*    iArr = mArr + M;                     // M
  size_t head = ((size_t)3 * NB + 2 * (size_t)M + 63) & ~(size_t)63;
  float*    rows = (float*)d_ws + head;          // 16*N floats (64B-aligned lines)

  int gN = (N + TPB - 1) / TPB;
  int gB = (NB + TPB - 1) / TPB;

  k_zero   <<<gB, TPB, 0, stream>>>(bcnt, NB);
  k_bcount <<<gN, TPB, 0, stream>>>(vox, bcnt, N);
  k_bscan  <<<1,  TPB, 0, stream>>>(bcnt, bofs, bcur, NB);
  k_build  <<<gN, TPB, 0, stream>>>(feat, conf, vox, tt, bcur, rows, W, N);
  k_breduce<<<NB, TPB, 0, stream>>>(rows, bofs, bcnt, F, mArr, iArr, M);
  k_wfinal <<<gN, TPB, 0, stream>>>(vox, mArr, iArr, W, N);
}